// Round 3
// baseline (73611.383 us; speedup 1.0000x reference)
//
#include <hip/hip_runtime.h>
#include <hip/hip_fp16.h>

// LSTM_54537494725306: 2-layer LSTM, T=2048, D=512, H=2048, OUT=64, fp32 in/out.
// R3: WEIGHT-STATIONARY. R2 showed the 104 MB fp16 working set will not stay
// cache-resident (53 MB/step from HBM at <35% BW, latency-bound). Register files
// hold 128 MB chip-wide, so each wave preloads its 48 KB of recurrent weights
// (Whh1/Wih2/Whh2 gate rows) into 192 packed-fp16 VGPRs once; Wih1 lives in LDS
// as fp32. Steady-state memory traffic = h-vector broadcasts only (~20 KB/CU/step).
// Same proven pipeline: phase p = layer1@p + layer2@(p-1) + y@(p-2), 1 grid
// barrier/phase; c1/c2 in registers; h double-buffered in ws.

#define T_STEPS 2048
#define DIM_D   512
#define DIM_H   2048
#define DIM_OUT 64
#define NWG     256
#define NTHR    512

#define N_WIH1 (4 * DIM_H * DIM_D)
#define N_WHH1 (4 * DIM_H * DIM_H)
#define N_WIH2 (4 * DIM_H * DIM_H)
#define N_WHH2 (4 * DIM_H * DIM_H)
#define N_WLIN (DIM_OUT * DIM_H)
#define WS_WEIGHT_OFF 65536

__device__ __forceinline__ float sigf(float x)   { return 1.0f / (1.0f + __expf(-x)); }
__device__ __forceinline__ float tanh_f(float x) { return 1.0f - 2.0f / (__expf(2.0f * x) + 1.0f); }

__device__ __forceinline__ float wave_reduce(float v) {
#pragma unroll
    for (int off = 32; off > 0; off >>= 1) v += __shfl_xor(v, off, 64);
    return v;
}

__device__ __forceinline__ float2 up2(unsigned int u) {
    return __half22float2(*(__half2*)&u);
}

// acc += dot(4 packed fp16 weights, 4 fp32 vector elems)
__device__ __forceinline__ float dot4h(uint2 w, float4 v, float acc) {
    float2 f0 = up2(w.x), f1 = up2(w.y);
    acc = fmaf(f0.x, v.x, acc);
    acc = fmaf(f0.y, v.y, acc);
    acc = fmaf(f1.x, v.z, acc);
    acc = fmaf(f1.y, v.w, acc);
    return acc;
}

// Two-level sense-free barrier (proven R1/R2).
__device__ __forceinline__ void grid_barrier(int* bar, int wg, int* sGen) {
    __syncthreads();
    if (threadIdx.x == 0) {
        const int g = *sGen;
        const int grp = wg >> 5;
        int a = __hip_atomic_fetch_add(&bar[grp * 32], 1, __ATOMIC_ACQ_REL, __HIP_MEMORY_SCOPE_AGENT);
        if (a == 31) {
            int r = __hip_atomic_fetch_add(&bar[256], 1, __ATOMIC_ACQ_REL, __HIP_MEMORY_SCOPE_AGENT);
            if (r == 7) {
#pragma unroll
                for (int i = 0; i < 8; ++i)
                    __hip_atomic_store(&bar[i * 32], 0, __ATOMIC_RELAXED, __HIP_MEMORY_SCOPE_AGENT);
                __hip_atomic_store(&bar[256], 0, __ATOMIC_RELAXED, __HIP_MEMORY_SCOPE_AGENT);
                __hip_atomic_store(&bar[288], g + 1, __ATOMIC_RELEASE, __HIP_MEMORY_SCOPE_AGENT);
            }
        }
        while (__hip_atomic_load(&bar[288], __ATOMIC_RELAXED, __HIP_MEMORY_SCOPE_AGENT) <= g) {
            __builtin_amdgcn_s_sleep(2);
        }
        __builtin_amdgcn_fence(__ATOMIC_ACQUIRE, "agent");
        *sGen = g + 1;
    }
    __syncthreads();
}

__global__ void lstm_init(int* bar, float* h1buf, float* h2buf) {
    int i = threadIdx.x + blockIdx.x * blockDim.x;
    if (i < 512) bar[i] = 0;
    if (i < 2 * DIM_H) { h1buf[i] = 0.0f; h2buf[i] = 0.0f; }
}

__global__ void convert_f16(const float* __restrict__ src, __half* __restrict__ dst, int n4) {
    int i = threadIdx.x + blockIdx.x * blockDim.x;
    if (i < n4) {
        float4 f = ((const float4*)src)[i];
        __half2 h01 = __floats2half2_rn(f.x, f.y);
        __half2 h23 = __floats2half2_rn(f.z, f.w);
        uint2 o;
        o.x = *(unsigned int*)&h01;
        o.y = *(unsigned int*)&h23;
        ((uint2*)dst)[i] = o;
    }
}

__global__ __launch_bounds__(NTHR, 2) void lstm_persist(
    const float* __restrict__ x,
    const __half* __restrict__ Wih1, const __half* __restrict__ Whh1,
    const float* __restrict__ bih1, const float* __restrict__ bhh1,
    const __half* __restrict__ Wih2, const __half* __restrict__ Whh2,
    const float* __restrict__ bih2, const float* __restrict__ bhh2,
    const __half* __restrict__ Wlin, const float* __restrict__ blin,
    float* __restrict__ out,
    int* bar, float* h1buf, float* h2buf)
{
    const int wg   = blockIdx.x;
    const int wave = threadIdx.x >> 6;
    const int lane = threadIdx.x & 63;
    const int unit = wg * 8 + wave;

    __shared__ int sGen;
    __shared__ float s_wi1[8][4][512];   // 64 KB: per-wave Wih1 gate rows, fp32
    if (threadIdx.x == 0) sGen = 0;

    const int r0 = unit, r1 = DIM_H + unit, r2 = 2 * DIM_H + unit, r3 = 3 * DIM_H + unit;
    const float b1_0 = bih1[r0] + bhh1[r0];
    const float b1_1 = bih1[r1] + bhh1[r1];
    const float b1_2 = bih1[r2] + bhh1[r2];
    const float b1_3 = bih1[r3] + bhh1[r3];
    const float b2_0 = bih2[r0] + bhh2[r0];
    const float b2_1 = bih2[r1] + bhh2[r1];
    const float b2_2 = bih2[r2] + bhh2[r2];
    const float b2_3 = bih2[r3] + bhh2[r3];

    // ---- preload recurrent weights into registers (192 packed VGPRs) ----
    uint2 rwh1[4][8], rwi2[4][8], rwh2[4][8];
#pragma unroll
    for (int r = 0; r < 4; ++r) {
        const size_t q = (size_t)r * DIM_H + unit;
        const __half* p1 = Whh1 + q * DIM_H;
        const __half* p2 = Wih2 + q * DIM_H;
        const __half* p3 = Whh2 + q * DIM_H;
#pragma unroll
        for (int c = 0; c < 8; ++c) {
            const int e = c * 256 + lane * 4;
            rwh1[r][c] = *(const uint2*)(p1 + e);
            rwi2[r][c] = *(const uint2*)(p2 + e);
            rwh2[r][c] = *(const uint2*)(p3 + e);
        }
    }
    // ---- Wih1 -> LDS (fp32) ----
#pragma unroll
    for (int r = 0; r < 4; ++r) {
        const __half* pw = Wih1 + ((size_t)r * DIM_H + unit) * DIM_D;
        uint4 u = *(const uint4*)(pw + lane * 8);
        float2 f0 = up2(u.x), f1 = up2(u.y), f2 = up2(u.z), f3 = up2(u.w);
        float* d = &s_wi1[wave][r][lane * 8];
        d[0] = f0.x; d[1] = f0.y; d[2] = f1.x; d[3] = f1.y;
        d[4] = f2.x; d[5] = f2.y; d[6] = f3.x; d[7] = f3.y;
    }
    __syncthreads();

    const bool  is_y = (wg < DIM_OUT) && (wave == 0);
    const float by   = (wg < DIM_OUT) ? blin[wg] : 0.0f;
    const __half* wy = Wlin + (size_t)(wg < DIM_OUT ? wg : 0) * DIM_H;

    float c1 = 0.0f, c2 = 0.0f;

    for (int p = 0; p < T_STEPS + 2; ++p) {
        const float* h1_prev  = h1buf + (size_t)((p + 1) & 1) * DIM_H;  // h1[p-1]
        float*       h1_cur   = h1buf + (size_t)(p & 1) * DIM_H;        // h1[p]
        const float* h2_prev2 = h2buf + (size_t)(p & 1) * DIM_H;        // h2[p-2]
        float*       h2_cur   = h2buf + (size_t)((p + 1) & 1) * DIM_H;  // h2[p-1]

        const bool l1 = (p < T_STEPS);
        const bool l2 = (p >= 1 && p <= T_STEPS);
        const bool yo = is_y && (p >= 2);

        float a0 = 0.f, a1 = 0.f, a2 = 0.f, a3 = 0.f;   // layer1 gates
        float g0 = 0.f, g1 = 0.f, g2 = 0.f, g3 = 0.f;   // layer2 gates

        // ---- layer1 x-part (LDS weights) ----
        if (l1) {
            const float* xp = x + (size_t)p * DIM_D;
#pragma unroll
            for (int c = 0; c < 2; ++c) {
                const int e = c * 256 + lane * 4;
                const float4 xv = *(const float4*)(xp + e);
                const float4 w0 = *(const float4*)&s_wi1[wave][0][e];
                const float4 w1 = *(const float4*)&s_wi1[wave][1][e];
                const float4 w2 = *(const float4*)&s_wi1[wave][2][e];
                const float4 w3 = *(const float4*)&s_wi1[wave][3][e];
                a0 = fmaf(w0.x, xv.x, fmaf(w0.y, xv.y, fmaf(w0.z, xv.z, fmaf(w0.w, xv.w, a0))));
                a1 = fmaf(w1.x, xv.x, fmaf(w1.y, xv.y, fmaf(w1.z, xv.z, fmaf(w1.w, xv.w, a1))));
                a2 = fmaf(w2.x, xv.x, fmaf(w2.y, xv.y, fmaf(w2.z, xv.z, fmaf(w2.w, xv.w, a2))));
                a3 = fmaf(w3.x, xv.x, fmaf(w3.y, xv.y, fmaf(w3.z, xv.z, fmaf(w3.w, xv.w, a3))));
            }
        }

        // ---- fused pass over h1_prev: layer1 Whh1 + layer2 Wih2 ----
        if (l1 || l2) {
#pragma unroll
            for (int c = 0; c < 8; ++c) {
                const float4 hv = *(const float4*)(h1_prev + c * 256 + lane * 4);
                if (l1) {
                    a0 = dot4h(rwh1[0][c], hv, a0);
                    a1 = dot4h(rwh1[1][c], hv, a1);
                    a2 = dot4h(rwh1[2][c], hv, a2);
                    a3 = dot4h(rwh1[3][c], hv, a3);
                }
                if (l2) {
                    g0 = dot4h(rwi2[0][c], hv, g0);
                    g1 = dot4h(rwi2[1][c], hv, g1);
                    g2 = dot4h(rwi2[2][c], hv, g2);
                    g3 = dot4h(rwi2[3][c], hv, g3);
                }
            }
        }

        if (l1) {
            a0 = wave_reduce(a0); a1 = wave_reduce(a1);
            a2 = wave_reduce(a2); a3 = wave_reduce(a3);
            const float gi = sigf(a0 + b1_0);
            const float gf = sigf(a1 + b1_1);
            const float gg = tanh_f(a2 + b1_2);
            const float go = sigf(a3 + b1_3);
            c1 = fmaf(gf, c1, gi * gg);
            if (lane == 0) h1_cur[unit] = go * tanh_f(c1);
        }

        // ---- pass over h2_prev2: layer2 Whh2 (+ fused y) ----
        float ay = 0.f;
        if (l2 || yo) {
#pragma unroll
            for (int c = 0; c < 8; ++c) {
                const int e = c * 256 + lane * 4;
                const float4 hv = *(const float4*)(h2_prev2 + e);
                if (l2) {
                    g0 = dot4h(rwh2[0][c], hv, g0);
                    g1 = dot4h(rwh2[1][c], hv, g1);
                    g2 = dot4h(rwh2[2][c], hv, g2);
                    g3 = dot4h(rwh2[3][c], hv, g3);
                }
                if (yo) {
                    const uint2 wv = *(const uint2*)(wy + e);
                    ay = dot4h(wv, hv, ay);
                }
            }
        }

        if (l2) {
            g0 = wave_reduce(g0); g1 = wave_reduce(g1);
            g2 = wave_reduce(g2); g3 = wave_reduce(g3);
            const float gi = sigf(g0 + b2_0);
            const float gf = sigf(g1 + b2_1);
            const float gg = tanh_f(g2 + b2_2);
            const float go = sigf(g3 + b2_3);
            c2 = fmaf(gf, c2, gi * gg);
            if (lane == 0) h2_cur[unit] = go * tanh_f(c2);
        }

        if (yo) {
            ay = wave_reduce(ay);
            if (lane == 0) out[(size_t)(p - 2) * DIM_OUT + wg] = ay + by;
        }

        grid_barrier(bar, wg, &sGen);
    }
}

extern "C" void kernel_launch(void* const* d_in, const int* in_sizes, int n_in,
                              void* d_out, int out_size, void* d_ws, size_t ws_size,
                              hipStream_t stream) {
    const float* x    = (const float*)d_in[0];
    const float* Wih1 = (const float*)d_in[1];
    const float* Whh1 = (const float*)d_in[2];
    const float* bih1 = (const float*)d_in[3];
    const float* bhh1 = (const float*)d_in[4];
    const float* Wih2 = (const float*)d_in[5];
    const float* Whh2 = (const float*)d_in[6];
    const float* bih2 = (const float*)d_in[7];
    const float* bhh2 = (const float*)d_in[8];
    const float* Wlin = (const float*)d_in[9];
    const float* blin = (const float*)d_in[10];
    float* out = (float*)d_out;

    int*   bar   = (int*)d_ws;
    float* h1buf = (float*)((char*)d_ws + 4096);
    float* h2buf = h1buf + 2 * DIM_H;

    lstm_init<<<16, 256, 0, stream>>>(bar, h1buf, h2buf);

    __half* hWih1 = (__half*)((char*)d_ws + WS_WEIGHT_OFF);
    __half* hWhh1 = hWih1 + N_WIH1;
    __half* hWih2 = hWhh1 + N_WHH1;
    __half* hWhh2 = hWih2 + N_WIH2;
    __half* hWlin = hWhh2 + N_WHH2;

    const float* srcs[5] = { Wih1, Whh1, Wih2, Whh2, Wlin };
    __half*      dsts[5] = { hWih1, hWhh1, hWih2, hWhh2, hWlin };
    const int    ns[5]   = { N_WIH1, N_WHH1, N_WIH2, N_WHH2, N_WLIN };
    for (int m = 0; m < 5; ++m) {
        int n4 = ns[m] / 4;
        convert_f16<<<(n4 + 255) / 256, 256, 0, stream>>>(srcs[m], dsts[m], n4);
    }

    const __half* cWih1 = hWih1; const __half* cWhh1 = hWhh1;
    const __half* cWih2 = hWih2; const __half* cWhh2 = hWhh2;
    const __half* cWlin = hWlin;
    void* args[] = {
        (void*)&x,
        (void*)&cWih1, (void*)&cWhh1, (void*)&bih1, (void*)&bhh1,
        (void*)&cWih2, (void*)&cWhh2, (void*)&bih2, (void*)&bhh2,
        (void*)&cWlin, (void*)&blin,
        (void*)&out, (void*)&bar, (void*)&h1buf, (void*)&h2buf
    };
    hipLaunchCooperativeKernel((const void*)lstm_persist, dim3(NWG), dim3(NTHR),
                               args, 0, stream);
}